// Round 1
// baseline (896.812 us; speedup 1.0000x reference)
//
#include <hip/hip_runtime.h>
#include <hip/hip_bf16.h>

#define B_      2048
#define R_      333
#define MAXI_   119
#define MAXO_   12
#define CONCAT_ 3325
#define E_      3328
#define TOTAL_  24696
#define HID_    1024
#define NREG_   300
#define NCLS_   180
#define EPS_    1e-5f

typedef __attribute__((ext_vector_type(8))) short bf16x8;
typedef __attribute__((ext_vector_type(4))) float f32x4;

static __device__ inline unsigned short f2bf(float f) {
  __hip_bfloat16 h = __float2bfloat16(f);
  unsigned short u;
  __builtin_memcpy(&u, &h, 2);
  return u;
}

// ---------------- layout: ROI starts / reduced starts ----------------
__global__ void layout_kernel(int* __restrict__ starts, int* __restrict__ red_starts) {
  if (threadIdx.x == 0 && blockIdx.x == 0) {
    int s = 0, rs = 0;
    for (int r = 0; r < R_; ++r) {
      starts[r] = s;
      red_starts[r] = rs;
      s += 30 + (7 * r) % 90;
      rs += (r == 332) ? 8 : (8 + r % 5);
    }
  }
}

// ---------------- f32 -> bf16 cast (vectorized) ----------------
__global__ __launch_bounds__(256) void cast_bf16_kernel(const float* __restrict__ src,
                                                        unsigned short* __restrict__ dst, int n4) {
  int i = blockIdx.x * 256 + threadIdx.x;
  if (i >= n4) return;
  float4 v = ((const float4*)src)[i];
  ushort4 o;
  o.x = f2bf(v.x); o.y = f2bf(v.y); o.z = f2bf(v.z); o.w = f2bf(v.w);
  ((ushort4*)dst)[i] = o;
}

// ---------------- ragged per-ROI encoder: yT[3325][2048] ----------------
__global__ __launch_bounds__(256) void encode_kernel(
    const float* __restrict__ x, const float* __restrict__ enc_W, const float* __restrict__ enc_b,
    const int* __restrict__ starts, const int* __restrict__ red_starts, float* __restrict__ yT) {
  int r  = blockIdx.x;
  int bt = blockIdx.y;
  __shared__ float xt[64][121];   // stride 121: 121%32=25, gcd(25,32)=1 -> conflict-free
  __shared__ float wt[12][121];
  __shared__ float bb[12];
  int size  = 30 + (7 * r) % 90;
  int red   = (r == 332) ? 8 : (8 + r % 5);
  int start = starts[r];
  int rs    = red_starts[r];
  int tid   = threadIdx.x;

  for (int idx = tid; idx < red * MAXI_; idx += 256) {
    int o = idx / MAXI_, i = idx % MAXI_;
    wt[o][i] = enc_W[((size_t)r * MAXO_ + o) * MAXI_ + i];
  }
  if (tid < red) bb[tid] = enc_b[r * MAXO_ + tid];

  int half = tid >> 7;       // 0..1
  int colt = tid & 127;
  int rowbase = bt * 64;
  for (int rr = half; rr < 64; rr += 2) {
    if (colt < size)
      xt[rr][colt] = x[(size_t)(rowbase + rr) * TOTAL_ + start + colt];
  }
  __syncthreads();

  int row = tid & 63;
  int oc0 = tid >> 6;        // 0..3
  for (int oc = oc0; oc < red; oc += 4) {
    float s = 0.f;
    for (int i = 0; i < size; ++i) s = fmaf(xt[row][i], wt[oc][i], s);
    yT[(size_t)(rs + oc) * B_ + rowbase + row] = s + bb[oc];
  }
}

// ---------------- per-feature batch stats over yT (coalesced) ----------------
__global__ __launch_bounds__(256) void colstats_T_kernel(const float* __restrict__ yT,
                                                         float* __restrict__ mean, float* __restrict__ rstd) {
  int c = blockIdx.x;
  const float* p = yT + (size_t)c * B_;
  float s = 0.f, s2 = 0.f;
  for (int i = threadIdx.x; i < B_; i += 256) { float v = p[i]; s += v; s2 = fmaf(v, v, s2); }
  for (int o = 32; o; o >>= 1) { s += __shfl_down(s, o); s2 += __shfl_down(s2, o); }
  __shared__ float rs_[4], rs2_[4];
  int w = threadIdx.x >> 6;
  if ((threadIdx.x & 63) == 0) { rs_[w] = s; rs2_[w] = s2; }
  __syncthreads();
  if (threadIdx.x == 0) {
    s = rs_[0] + rs_[1] + rs_[2] + rs_[3];
    s2 = rs2_[0] + rs2_[1] + rs2_[2] + rs2_[3];
    float m = s / B_;
    float v = s2 / B_ - m * m;
    mean[c] = m;
    rstd[c] = rsqrtf(v + EPS_);
  }
}

// ---------------- BN1 + LeakyReLU(0.3) + transpose + pad-col write (bf16) ----------------
__global__ __launch_bounds__(256) void bn1_transpose_kernel(
    const float* __restrict__ yT, const float* __restrict__ mean, const float* __restrict__ rstd,
    const float* __restrict__ g, const float* __restrict__ bb, unsigned short* __restrict__ Y) {
  __shared__ float tile[64][65];
  int c0 = blockIdx.x * 64, b0 = blockIdx.y * 64;
  int t = threadIdx.x;
  int bi = t & 63, ci0 = t >> 6;
  for (int ci = ci0; ci < 64; ci += 4) {
    int c = c0 + ci;
    float v = 0.f;
    if (c < CONCAT_) {
      v = (yT[(size_t)c * B_ + b0 + bi] - mean[c]) * rstd[c] * g[c] + bb[c];
      v = v > 0.f ? v : 0.3f * v;
    }
    tile[ci][bi] = v;
  }
  __syncthreads();
  int cj = t & 63, bj0 = t >> 6;
  for (int bj = bj0; bj < 64; bj += 4) {
    int c = c0 + cj;
    if (c < CONCAT_)
      Y[(size_t)(b0 + bj) * E_ + c + 1] = f2bf(tile[cj][bj]);
  }
}

__global__ __launch_bounds__(256) void pad_zero_kernel(unsigned short* __restrict__ Y) {
  int i = blockIdx.x * 256 + threadIdx.x;
  if (i >= B_ * 3) return;
  int b = i / 3, which = i % 3;
  int c = (which == 0) ? 0 : ((which == 1) ? 3326 : 3327);
  Y[(size_t)b * E_ + c] = 0;  // +0.0f in bf16 is bit pattern 0
}

// ---------------- bf16 MFMA GEMM: C[M][N] = A[M][K] @ W[N][K]^T + bias ----------------
// block = 4 waves, 128x128 tile; wave = 64x64 = 4x4 fragments of 16x16x32 MFMA.
template <bool OUT_BF16>
__global__ __launch_bounds__(256) void gemm_bt_kernel(
    const unsigned short* __restrict__ A, const unsigned short* __restrict__ W,
    const float* __restrict__ bias, float* __restrict__ Cf, unsigned short* __restrict__ Cb,
    int M, int N, int K) {
  int wid  = threadIdx.x >> 6;
  int lane = threadIdx.x & 63;
  int wr = wid >> 1, wc = wid & 1;
  int row0 = blockIdx.y * 128 + wr * 64;
  int col0 = blockIdx.x * 128 + wc * 64;
  int lr = lane & 15;
  int kg = lane >> 4;

  f32x4 acc[4][4] = {};
  const bf16x8 bzero = {0, 0, 0, 0, 0, 0, 0, 0};

  for (int kc = 0; kc < K; kc += 32) {
    int kk = kc + kg * 8;
    bf16x8 a[4], b[4];
#pragma unroll
    for (int f = 0; f < 4; ++f) {
      int r = row0 + f * 16 + lr;                // M always multiple of 128 here
      a[f] = *(const bf16x8*)(A + (size_t)r * K + kk);
      int n = col0 + f * 16 + lr;
      b[f] = (n < N) ? *(const bf16x8*)(W + (size_t)n * K + kk) : bzero;
    }
#pragma unroll
    for (int i = 0; i < 4; ++i)
#pragma unroll
      for (int j = 0; j < 4; ++j)
        acc[i][j] = __builtin_amdgcn_mfma_f32_16x16x32_bf16(a[i], b[j], acc[i][j], 0, 0, 0);
  }

  // C/D: col = lane&15, row = (lane>>4)*4 + reg   [m89-verified]
#pragma unroll
  for (int j = 0; j < 4; ++j) {
    int ccol = col0 + j * 16 + (lane & 15);
    if (ccol >= N) continue;
    float bv = bias ? bias[ccol] : 0.f;
#pragma unroll
    for (int i = 0; i < 4; ++i) {
#pragma unroll
      for (int reg = 0; reg < 4; ++reg) {
        int crow = row0 + i * 16 + (lane >> 4) * 4 + reg;
        float v = acc[i][j][reg] + bv;
        if (OUT_BF16) Cb[(size_t)crow * N + ccol] = f2bf(v);
        else          Cf[(size_t)crow * N + ccol] = v;
      }
    }
  }
}

// ---------------- BN2 stats over row-major Z (two-stage, deterministic) ----------------
__global__ __launch_bounds__(256) void colstats_partial_kernel(
    const float* __restrict__ Z, float* __restrict__ pS, float* __restrict__ pS2,
    int M, int C, int rowsPerBlock) {
  int c = blockIdx.x * 256 + threadIdx.x;
  if (c >= C) return;
  int r0 = blockIdx.y * rowsPerBlock;
  float s = 0.f, s2 = 0.f;
  for (int r = r0; r < r0 + rowsPerBlock; ++r) {
    float v = Z[(size_t)r * C + c];
    s += v; s2 = fmaf(v, v, s2);
  }
  pS[blockIdx.y * C + c] = s;
  pS2[blockIdx.y * C + c] = s2;
}

__global__ __launch_bounds__(256) void colstats_final_kernel(
    const float* __restrict__ pS, const float* __restrict__ pS2,
    float* __restrict__ mean, float* __restrict__ rstd, int C, int nrb, int M) {
  int c = blockIdx.x * 256 + threadIdx.x;
  if (c >= C) return;
  float s = 0.f, s2 = 0.f;
  for (int i = 0; i < nrb; ++i) { s += pS[i * C + c]; s2 += pS2[i * C + c]; }
  float m = s / M;
  float v = s2 / M - m * m;
  mean[c] = m;
  rstd[c] = rsqrtf(v + EPS_);
}

// ---------------- BN2 apply + LeakyReLU(0.1) -> bf16 ----------------
__global__ __launch_bounds__(256) void bn2_apply_kernel(
    const float* __restrict__ Z, const float* __restrict__ mean, const float* __restrict__ rstd,
    const float* __restrict__ g, const float* __restrict__ bb, unsigned short* __restrict__ R) {
  int i = blockIdx.x * 256 + threadIdx.x;
  int c = i & (HID_ - 1);
  float v = (Z[i] - mean[c]) * rstd[c] * g[c] + bb[c];
  v = v > 0.f ? v : 0.1f * v;
  R[i] = f2bf(v);
}

// ---------------- classifier: y_pred = softmax(reg @ Wc^T + bc) ----------------
__global__ __launch_bounds__(256) void classifier_kernel(
    const float* __restrict__ reg, const float* __restrict__ Wc, const float* __restrict__ bc,
    float* __restrict__ ypred) {
  int b = blockIdx.x;
  __shared__ __align__(16) float rrow[NREG_];
  __shared__ float sl[256];
  int tid = threadIdx.x;
  for (int i = tid; i < NREG_; i += 256) rrow[i] = reg[(size_t)b * NREG_ + i];
  __syncthreads();
  float s = -1e30f;
  if (tid < NCLS_) {
    const float* w = Wc + (size_t)tid * NREG_;
    float acc = 0.f;
    for (int k = 0; k < NREG_; k += 4) {
      float4 wv = *(const float4*)(w + k);
      float4 rv = *(const float4*)(&rrow[k]);
      acc = fmaf(wv.x, rv.x, acc); acc = fmaf(wv.y, rv.y, acc);
      acc = fmaf(wv.z, rv.z, acc); acc = fmaf(wv.w, rv.w, acc);
    }
    s = acc + bc[tid];
  }
  sl[tid] = s;
  __syncthreads();
  for (int o = 128; o > 0; o >>= 1) {
    if (tid < o) sl[tid] = fmaxf(sl[tid], sl[tid + o]);
    __syncthreads();
  }
  float mx = sl[0];
  __syncthreads();
  float e = (tid < NCLS_) ? __expf(s - mx) : 0.f;
  sl[tid] = e;
  __syncthreads();
  for (int o = 128; o > 0; o >>= 1) {
    if (tid < o) sl[tid] += sl[tid + o];
    __syncthreads();
  }
  if (tid < NCLS_) ypred[(size_t)b * NCLS_ + tid] = e / sl[0];
}

// ---------------- host orchestration ----------------
extern "C" void kernel_launch(void* const* d_in, const int* in_sizes, int n_in,
                              void* d_out, int out_size, void* d_ws, size_t ws_size,
                              hipStream_t stream) {
  const float* x     = (const float*)d_in[0];
  const float* enc_W = (const float*)d_in[1];
  const float* enc_b = (const float*)d_in[2];
  const float* bn1_g = (const float*)d_in[3];
  const float* bn1_b = (const float*)d_in[4];
  const float* Wqkv  = (const float*)d_in[5];
  const float* bqkv  = (const float*)d_in[6];
  const float* Wo    = (const float*)d_in[7];
  const float* bo    = (const float*)d_in[8];
  const float* W1    = (const float*)d_in[9];
  const float* b1    = (const float*)d_in[10];
  const float* bn2_g = (const float*)d_in[11];
  const float* bn2_b = (const float*)d_in[12];
  const float* W2    = (const float*)d_in[13];
  const float* b2    = (const float*)d_in[14];
  const float* Wc    = (const float*)d_in[15];
  const float* bc    = (const float*)d_in[16];

  char* ws = (char*)d_ws;
  size_t off = 0;
  auto alloc = [&](size_t bytes) -> void* {
    void* p = ws + off;
    off += (bytes + 255) & ~(size_t)255;
    return p;
  };

  float*          yT     = (float*)alloc((size_t)CONCAT_ * B_ * 4);       // 27.2MB (reused for Z)
  float*          mean1  = (float*)alloc(CONCAT_ * 4);
  float*          rstd1  = (float*)alloc(CONCAT_ * 4);
  unsigned short* Ybf    = (unsigned short*)alloc((size_t)B_ * E_ * 2);   // 13.6MB (reused for O)
  unsigned short* Vbf    = (unsigned short*)alloc((size_t)B_ * E_ * 2);   // 13.6MB (reused for R)
  unsigned short* Wv_bf  = (unsigned short*)alloc((size_t)E_ * E_ * 2);   // 22.2MB
  unsigned short* Wo_bf  = (unsigned short*)alloc((size_t)E_ * E_ * 2);   // 22.2MB
  unsigned short* W1_bf  = (unsigned short*)alloc((size_t)HID_ * E_ * 2); // 6.8MB
  unsigned short* W2_bf  = (unsigned short*)alloc((size_t)NREG_ * HID_ * 2);
  float*          partS  = (float*)alloc(16 * HID_ * 4);
  float*          partS2 = (float*)alloc(16 * HID_ * 4);
  float*          mean2  = (float*)alloc(HID_ * 4);
  float*          rstd2  = (float*)alloc(HID_ * 4);
  int*            starts = (int*)alloc(R_ * 4);
  int*            redst  = (int*)alloc(R_ * 4);

  // buffer reuse (lifetimes disjoint):
  unsigned short* Obf = Ybf;   // Y dead after GEMM1
  float*          Z   = yT;    // yT dead after bn1_transpose
  unsigned short* Rbf = Vbf;   // V dead after GEMM2

  layout_kernel<<<1, 1, 0, stream>>>(starts, redst);

  int n4 = (E_ * E_) / 4;
  cast_bf16_kernel<<<(n4 + 255) / 256, 256, 0, stream>>>(Wqkv + (size_t)2 * E_ * E_, Wv_bf, n4);
  cast_bf16_kernel<<<(n4 + 255) / 256, 256, 0, stream>>>(Wo, Wo_bf, n4);
  n4 = (HID_ * E_) / 4;
  cast_bf16_kernel<<<(n4 + 255) / 256, 256, 0, stream>>>(W1, W1_bf, n4);
  n4 = (NREG_ * HID_) / 4;
  cast_bf16_kernel<<<(n4 + 255) / 256, 256, 0, stream>>>(W2, W2_bf, n4);

  encode_kernel<<<dim3(R_, B_ / 64), 256, 0, stream>>>(x, enc_W, enc_b, starts, redst, yT);
  colstats_T_kernel<<<CONCAT_, 256, 0, stream>>>(yT, mean1, rstd1);
  bn1_transpose_kernel<<<dim3((CONCAT_ + 63) / 64, B_ / 64), 256, 0, stream>>>(yT, mean1, rstd1, bn1_g, bn1_b, Ybf);
  pad_zero_kernel<<<(B_ * 3 + 255) / 256, 256, 0, stream>>>(Ybf);

  // V = Y @ Wv^T + bv   (only the v-chunk of qkv is ever needed: L=1 softmax == 1)
  gemm_bt_kernel<true><<<dim3(E_ / 128, B_ / 128), 256, 0, stream>>>(
      Ybf, Wv_bf, bqkv + 2 * E_, nullptr, Vbf, B_, E_, E_);
  // O = V @ Wo^T + bo
  gemm_bt_kernel<true><<<dim3(E_ / 128, B_ / 128), 256, 0, stream>>>(
      Vbf, Wo_bf, bo, nullptr, Obf, B_, E_, E_);
  // Z = O @ W1^T + b1  (f32 out for BN stats)
  gemm_bt_kernel<false><<<dim3(HID_ / 128, B_ / 128), 256, 0, stream>>>(
      Obf, W1_bf, b1, Z, nullptr, B_, HID_, E_);

  colstats_partial_kernel<<<dim3(HID_ / 256, 16), 256, 0, stream>>>(Z, partS, partS2, B_, HID_, B_ / 16);
  colstats_final_kernel<<<HID_ / 256, 256, 0, stream>>>(partS, partS2, mean2, rstd2, HID_, 16, B_);
  bn2_apply_kernel<<<(B_ * HID_) / 256, 256, 0, stream>>>(Z, mean2, rstd2, bn2_g, bn2_b, Rbf);

  // reg_out = R @ W2^T + b2  -> d_out[0 : 2048*300)
  float* reg_out = (float*)d_out;
  gemm_bt_kernel<false><<<dim3((NREG_ + 127) / 128, B_ / 128), 256, 0, stream>>>(
      Rbf, W2_bf, b2, reg_out, nullptr, B_, NREG_, HID_);

  // y_pred = softmax(reg_out @ Wc^T + bc) -> d_out[2048*300 : )
  classifier_kernel<<<B_, 256, 0, stream>>>(reg_out, Wc, bc, reg_out + (size_t)B_ * NREG_);
}

// Round 3
// 546.313 us; speedup vs baseline: 1.6416x; 1.6416x over previous
//
#include <hip/hip_runtime.h>
#include <hip/hip_bf16.h>

#define B_      2048
#define R_      333
#define MAXI_   119
#define MAXO_   12
#define CONCAT_ 3325
#define E_      3328
#define TOTAL_  24696
#define HID_    1024
#define NREG_   300
#define NCLS_   180
#define EPS_    1e-5f
#define NSLOT_  16   // BN1 partial-stat slots (2048 rows / 128 rows-per-wave)
#define PSTR_   3328 // partial-stat stride

typedef __attribute__((ext_vector_type(8))) short bf16x8;
typedef __attribute__((ext_vector_type(4))) float f32x4;

static __device__ inline unsigned short f2bf(float f) {
  __hip_bfloat16 h = __float2bfloat16(f);
  unsigned short u;
  __builtin_memcpy(&u, &h, 2);
  return u;
}

// ---------------- layout: ROI starts / reduced starts ----------------
__global__ void layout_kernel(int* __restrict__ starts, int* __restrict__ red_starts) {
  if (threadIdx.x == 0 && blockIdx.x == 0) {
    int s = 0, rs = 0;
    for (int r = 0; r < R_; ++r) {
      starts[r] = s;
      red_starts[r] = rs;
      s += 30 + (7 * r) % 90;
      rs += (r == 332) ? 8 : (8 + r % 5);
    }
  }
}

// ---------------- f32 -> bf16 cast (vectorized) ----------------
__global__ __launch_bounds__(256) void cast_bf16_kernel(const float* __restrict__ src,
                                                        unsigned short* __restrict__ dst, int n4) {
  int i = blockIdx.x * 256 + threadIdx.x;
  if (i >= n4) return;
  float4 v = ((const float4*)src)[i];
  ushort4 o;
  o.x = f2bf(v.x); o.y = f2bf(v.y); o.z = f2bf(v.z); o.w = f2bf(v.w);
  ((ushort4*)dst)[i] = o;
}

// ---------------- ragged per-ROI encoder via MFMA, no LDS ----------------
__global__ __launch_bounds__(256) void encode_kernel(
    const float* __restrict__ x, const float* __restrict__ enc_W, const float* __restrict__ enc_b,
    const int* __restrict__ starts, const int* __restrict__ red_starts,
    float* __restrict__ yT, float* __restrict__ pS1, float* __restrict__ pS2) {
  int r    = blockIdx.x;
  int wid  = threadIdx.x >> 6;
  int lane = threadIdx.x & 63;
  int slot = blockIdx.y * 4 + wid;          // 0..15
  int lr = lane & 15, kg = lane >> 4;

  int size  = 30 + (7 * r) % 90;
  int red   = (r == 332) ? 8 : (8 + r % 5);
  int start = starts[r];
  int rs    = red_starts[r];

  // --- A fragments: weights, lane row = oc = lr, k = kg*8+e (4 K-chunks) ---
  bf16x8 wf[4];
#pragma unroll
  for (int kc = 0; kc < 4; ++kc) {
    bf16x8 w = {0, 0, 0, 0, 0, 0, 0, 0};
    if (kc * 32 < size) {
#pragma unroll
      for (int e = 0; e < 8; ++e) {
        int k = kc * 32 + kg * 8 + e;
        float wv = 0.f;
        if (lr < MAXO_ && k < MAXI_) wv = enc_W[((size_t)r * MAXO_ + lr) * MAXI_ + k];
        w[e] = (short)f2bf(wv);
      }
    }
    wf[kc] = w;
  }
  // bias per C-reg (C layout: col=b=lane&15, row=oc=kg*4+reg)
  float bofs[4];
#pragma unroll
  for (int reg = 0; reg < 4; ++reg) {
    int oc = kg * 4 + reg;
    bofs[reg] = (oc < red) ? enc_b[r * MAXO_ + oc] : 0.f;
  }

  float s1v[4] = {0.f, 0.f, 0.f, 0.f}, s2v[4] = {0.f, 0.f, 0.f, 0.f};

  for (int t = 0; t < 8; ++t) {             // 8 b-tiles of 16 rows
    int b0 = slot * 128 + t * 16;
    const float* xrow = x + (size_t)(b0 + lr) * TOTAL_ + start;
    f32x4 acc = {0.f, 0.f, 0.f, 0.f};
#pragma unroll
    for (int kc = 0; kc < 4; ++kc) {
      if (kc * 32 < size) {
        int kbase = kc * 32 + kg * 8;
        float xv[8];
        if (kbase + 8 <= size) {
#pragma unroll
          for (int e = 0; e < 8; ++e) xv[e] = xrow[kbase + e];
        } else {
#pragma unroll
          for (int e = 0; e < 8; ++e) xv[e] = (kbase + e < size) ? xrow[kbase + e] : 0.f;
        }
        bf16x8 xf;
#pragma unroll
        for (int e = 0; e < 8; ++e) xf[e] = (short)f2bf(xv[e]);
        acc = __builtin_amdgcn_mfma_f32_16x16x32_bf16(wf[kc], xf, acc, 0, 0, 0);
      }
    }
#pragma unroll
    for (int reg = 0; reg < 4; ++reg) {
      int oc = kg * 4 + reg;
      if (oc < red) {
        float v = acc[reg] + bofs[reg];
        yT[(size_t)(rs + oc) * B_ + b0 + lr] = v;
        s1v[reg] += v;
        s2v[reg] = fmaf(v, v, s2v[reg]);
      }
    }
  }
  // reduce stats over the 16 b-lanes in each lane-group
#pragma unroll
  for (int reg = 0; reg < 4; ++reg) {
    float a = s1v[reg], c = s2v[reg];
#pragma unroll
    for (int m = 1; m <= 8; m <<= 1) { a += __shfl_xor(a, m); c += __shfl_xor(c, m); }
    int oc = kg * 4 + reg;
    if (lr == 0 && oc < red) {
      pS1[slot * PSTR_ + rs + oc] = a;
      pS2[slot * PSTR_ + rs + oc] = c;
    }
  }
}

// ---------------- BN1 stats finalize (16 slot-partials -> mean/rstd) ----------------
__global__ __launch_bounds__(256) void bn1_stats_kernel(const float* __restrict__ pS1,
                                                        const float* __restrict__ pS2,
                                                        float* __restrict__ mean, float* __restrict__ rstd) {
  int c = blockIdx.x * 256 + threadIdx.x;
  if (c >= CONCAT_) return;
  float s = 0.f, s2 = 0.f;
#pragma unroll
  for (int i = 0; i < NSLOT_; ++i) { s += pS1[i * PSTR_ + c]; s2 += pS2[i * PSTR_ + c]; }
  float m = s / B_;
  float v = s2 / B_ - m * m;
  mean[c] = m;
  rstd[c] = rsqrtf(v + EPS_);
}

// ---------------- BN1 + LeakyReLU(0.3) + transpose + pad-col write (bf16) ----------------
__global__ __launch_bounds__(256) void bn1_transpose_kernel(
    const float* __restrict__ yT, const float* __restrict__ mean, const float* __restrict__ rstd,
    const float* __restrict__ g, const float* __restrict__ bb, unsigned short* __restrict__ Y) {
  __shared__ float tile[64][65];
  int c0 = blockIdx.x * 64, b0 = blockIdx.y * 64;
  int t = threadIdx.x;
  int bi = t & 63, ci0 = t >> 6;
  for (int ci = ci0; ci < 64; ci += 4) {
    int c = c0 + ci;
    float v = 0.f;
    if (c < CONCAT_) {
      v = (yT[(size_t)c * B_ + b0 + bi] - mean[c]) * rstd[c] * g[c] + bb[c];
      v = v > 0.f ? v : 0.3f * v;
    }
    tile[ci][bi] = v;
  }
  __syncthreads();
  int cj = t & 63, bj0 = t >> 6;
  for (int bj = bj0; bj < 64; bj += 4) {
    int c = c0 + cj;
    if (c < CONCAT_)
      Y[(size_t)(b0 + bj) * E_ + c + 1] = f2bf(tile[cj][bj]);
  }
}

__global__ __launch_bounds__(256) void pad_zero_kernel(unsigned short* __restrict__ Y) {
  int i = blockIdx.x * 256 + threadIdx.x;
  if (i >= B_ * 3) return;
  int b = i / 3, which = i % 3;
  int c = (which == 0) ? 0 : ((which == 1) ? 3326 : 3327);
  Y[(size_t)b * E_ + c] = 0;
}

// ---------------- m97-style bf16 MFMA GEMM: C = A[M][K] @ W[N][K]^T + bias ----------------
// 128x128 tile, BK=32, global_load_lds(16B) staging x2 per operand (8KB tile), 2-barrier K-loop.
template <bool OUT_BF16>
__global__ __launch_bounds__(256) void gemm_lds_kernel(
    const unsigned short* __restrict__ A, const unsigned short* __restrict__ W,
    const float* __restrict__ bias, float* __restrict__ Cf, unsigned short* __restrict__ Cb,
    int M, int N, int K) {
  __shared__ unsigned short a_lds[128 * 32];   // 8192 B
  __shared__ unsigned short b_lds[128 * 32];
  int tid = threadIdx.x;
  int wid = tid >> 6, lane = tid & 63;
  int wr = wid >> 1, wc = wid & 1;
  int row0 = blockIdx.y * 128, col0 = blockIdx.x * 128;
  int lr = lane & 15, kg = lane >> 4;

  // staging: 256 threads x 16B = 4096B per issue -> 2 issues per 8192B tile.
  // issue 0: rows 0..63 (thread t -> row t>>2, k (t&3)*8); issue 1: rows 64..127.
  int srow = tid >> 2, sk = (tid & 3) * 8;
  const unsigned short* aptr0 = A + (size_t)(row0 + srow) * K + sk;
  const unsigned short* aptr1 = A + (size_t)(row0 + 64 + srow) * K + sk;
  int bcol0 = col0 + srow;      if (bcol0 > N - 1) bcol0 = N - 1;  // N-tail clamp (discarded)
  int bcol1 = col0 + 64 + srow; if (bcol1 > N - 1) bcol1 = N - 1;
  const unsigned short* bptr0 = W + (size_t)bcol0 * K + sk;
  const unsigned short* bptr1 = W + (size_t)bcol1 * K + sk;
  unsigned short* adst0 = a_lds + wid * 512;          // wave-uniform base; HW adds lane*16B
  unsigned short* adst1 = a_lds + 2048 + wid * 512;   // +4096 B
  unsigned short* bdst0 = b_lds + wid * 512;
  unsigned short* bdst1 = b_lds + 2048 + wid * 512;

  f32x4 acc[4][4] = {};

  for (int kc = 0; kc < K; kc += 32) {
    __syncthreads();   // previous tile's reads done before overwrite
    __builtin_amdgcn_global_load_lds((const __attribute__((address_space(1))) void*)(aptr0 + kc),
                                     (__attribute__((address_space(3))) void*)adst0, 16, 0, 0);
    __builtin_amdgcn_global_load_lds((const __attribute__((address_space(1))) void*)(aptr1 + kc),
                                     (__attribute__((address_space(3))) void*)adst1, 16, 0, 0);
    __builtin_amdgcn_global_load_lds((const __attribute__((address_space(1))) void*)(bptr0 + kc),
                                     (__attribute__((address_space(3))) void*)bdst0, 16, 0, 0);
    __builtin_amdgcn_global_load_lds((const __attribute__((address_space(1))) void*)(bptr1 + kc),
                                     (__attribute__((address_space(3))) void*)bdst1, 16, 0, 0);
    __syncthreads();   // compiler drains vmcnt(0) before barrier -> tile resident
    bf16x8 a[4], b[4];
#pragma unroll
    for (int f = 0; f < 4; ++f) {
      a[f] = *(const bf16x8*)&a_lds[(wr * 64 + f * 16 + lr) * 32 + kg * 8];
      b[f] = *(const bf16x8*)&b_lds[(wc * 64 + f * 16 + lr) * 32 + kg * 8];
    }
#pragma unroll
    for (int i = 0; i < 4; ++i)
#pragma unroll
      for (int j = 0; j < 4; ++j)
        acc[i][j] = __builtin_amdgcn_mfma_f32_16x16x32_bf16(a[i], b[j], acc[i][j], 0, 0, 0);
  }

  // C/D: col = lane&15, row = (lane>>4)*4 + reg
#pragma unroll
  for (int j = 0; j < 4; ++j) {
    int ccol = col0 + wc * 64 + j * 16 + lr;
    if (ccol >= N) continue;
    float bv = bias[ccol];
#pragma unroll
    for (int i = 0; i < 4; ++i) {
#pragma unroll
      for (int reg = 0; reg < 4; ++reg) {
        int crow = row0 + wr * 64 + i * 16 + kg * 4 + reg;
        float v = acc[i][j][reg] + bv;
        if (OUT_BF16) Cb[(size_t)crow * N + ccol] = f2bf(v);
        else          Cf[(size_t)crow * N + ccol] = v;
      }
    }
  }
}

// ---------------- BN2 stats over row-major Z (two-stage, deterministic) ----------------
__global__ __launch_bounds__(256) void colstats_partial_kernel(
    const float* __restrict__ Z, float* __restrict__ pS, float* __restrict__ pS2,
    int M, int C, int rowsPerBlock) {
  int c = blockIdx.x * 256 + threadIdx.x;
  if (c >= C) return;
  int r0 = blockIdx.y * rowsPerBlock;
  float s = 0.f, s2 = 0.f;
  for (int r = r0; r < r0 + rowsPerBlock; ++r) {
    float v = Z[(size_t)r * C + c];
    s += v; s2 = fmaf(v, v, s2);
  }
  pS[blockIdx.y * C + c] = s;
  pS2[blockIdx.y * C + c] = s2;
}

__global__ __launch_bounds__(256) void colstats_final_kernel(
    const float* __restrict__ pS, const float* __restrict__ pS2,
    float* __restrict__ mean, float* __restrict__ rstd, int C, int nrb, int M) {
  int c = blockIdx.x * 256 + threadIdx.x;
  if (c >= C) return;
  float s = 0.f, s2 = 0.f;
  for (int i = 0; i < nrb; ++i) { s += pS[i * C + c]; s2 += pS2[i * C + c]; }
  float m = s / M;
  float v = s2 / M - m * m;
  mean[c] = m;
  rstd[c] = rsqrtf(v + EPS_);
}

// ---------------- BN2 apply + LeakyReLU(0.1) -> bf16 ----------------
__global__ __launch_bounds__(256) void bn2_apply_kernel(
    const float* __restrict__ Z, const float* __restrict__ mean, const float* __restrict__ rstd,
    const float* __restrict__ g, const float* __restrict__ bb, unsigned short* __restrict__ R) {
  int i = blockIdx.x * 256 + threadIdx.x;
  int c = i & (HID_ - 1);
  float v = (Z[i] - mean[c]) * rstd[c] * g[c] + bb[c];
  v = v > 0.f ? v : 0.1f * v;
  R[i] = f2bf(v);
}

// ---------------- classifier: y_pred = softmax(reg @ Wc^T + bc) ----------------
__global__ __launch_bounds__(256) void classifier_kernel(
    const float* __restrict__ reg, const float* __restrict__ Wc, const float* __restrict__ bc,
    float* __restrict__ ypred) {
  int b = blockIdx.x;
  __shared__ __align__(16) float rrow[NREG_];
  __shared__ float sl[256];
  int tid = threadIdx.x;
  for (int i = tid; i < NREG_; i += 256) rrow[i] = reg[(size_t)b * NREG_ + i];
  __syncthreads();
  float s = -1e30f;
  if (tid < NCLS_) {
    const float* w = Wc + (size_t)tid * NREG_;
    float acc = 0.f;
    for (int k = 0; k < NREG_; k += 4) {
      float4 wv = *(const float4*)(w + k);
      float4 rv = *(const float4*)(&rrow[k]);
      acc = fmaf(wv.x, rv.x, acc); acc = fmaf(wv.y, rv.y, acc);
      acc = fmaf(wv.z, rv.z, acc); acc = fmaf(wv.w, rv.w, acc);
    }
    s = acc + bc[tid];
  }
  sl[tid] = s;
  __syncthreads();
  for (int o = 128; o > 0; o >>= 1) {
    if (tid < o) sl[tid] = fmaxf(sl[tid], sl[tid + o]);
    __syncthreads();
  }
  float mx = sl[0];
  __syncthreads();
  float e = (tid < NCLS_) ? __expf(s - mx) : 0.f;
  sl[tid] = e;
  __syncthreads();
  for (int o = 128; o > 0; o >>= 1) {
    if (tid < o) sl[tid] += sl[tid + o];
    __syncthreads();
  }
  if (tid < NCLS_) ypred[(size_t)b * NCLS_ + tid] = e / sl[0];
}

// ---------------- host orchestration ----------------
extern "C" void kernel_launch(void* const* d_in, const int* in_sizes, int n_in,
                              void* d_out, int out_size, void* d_ws, size_t ws_size,
                              hipStream_t stream) {
  const float* x     = (const float*)d_in[0];
  const float* enc_W = (const float*)d_in[1];
  const float* enc_b = (const float*)d_in[2];
  const float* bn1_g = (const float*)d_in[3];
  const float* bn1_b = (const float*)d_in[4];
  const float* Wqkv  = (const float*)d_in[5];
  const float* bqkv  = (const float*)d_in[6];
  const float* Wo    = (const float*)d_in[7];
  const float* bo    = (const float*)d_in[8];
  const float* W1    = (const float*)d_in[9];
  const float* b1    = (const float*)d_in[10];
  const float* bn2_g = (const float*)d_in[11];
  const float* bn2_b = (const float*)d_in[12];
  const float* W2    = (const float*)d_in[13];
  const float* b2    = (const float*)d_in[14];
  const float* Wc    = (const float*)d_in[15];
  const float* bc    = (const float*)d_in[16];

  char* ws = (char*)d_ws;
  size_t off = 0;
  auto alloc = [&](size_t bytes) -> void* {
    void* p = ws + off;
    off += (bytes + 255) & ~(size_t)255;
    return p;
  };

  float*          yT     = (float*)alloc((size_t)CONCAT_ * B_ * 4);       // reused for Z
  float*          pS1b   = (float*)alloc(NSLOT_ * PSTR_ * 4);
  float*          pS2b   = (float*)alloc(NSLOT_ * PSTR_ * 4);
  float*          mean1  = (float*)alloc(CONCAT_ * 4);
  float*          rstd1  = (float*)alloc(CONCAT_ * 4);
  unsigned short* Ybf    = (unsigned short*)alloc((size_t)B_ * E_ * 2);   // reused for O
  unsigned short* Vbf    = (unsigned short*)alloc((size_t)B_ * E_ * 2);   // reused for R
  unsigned short* Wv_bf  = (unsigned short*)alloc((size_t)E_ * E_ * 2);
  unsigned short* Wo_bf  = (unsigned short*)alloc((size_t)E_ * E_ * 2);
  unsigned short* W1_bf  = (unsigned short*)alloc((size_t)HID_ * E_ * 2);
  unsigned short* W2_bf  = (unsigned short*)alloc((size_t)NREG_ * HID_ * 2);
  float*          partS  = (float*)alloc(16 * HID_ * 4);
  float*          partS2 = (float*)alloc(16 * HID_ * 4);
  float*          mean2  = (float*)alloc(HID_ * 4);
  float*          rstd2  = (float*)alloc(HID_ * 4);
  int*            starts = (int*)alloc(R_ * 4);
  int*            redst  = (int*)alloc(R_ * 4);

  unsigned short* Obf = Ybf;
  float*          Z   = yT;
  unsigned short* Rbf = Vbf;

  layout_kernel<<<1, 1, 0, stream>>>(starts, redst);

  int n4 = (E_ * E_) / 4;
  cast_bf16_kernel<<<(n4 + 255) / 256, 256, 0, stream>>>(Wqkv + (size_t)2 * E_ * E_, Wv_bf, n4);
  cast_bf16_kernel<<<(n4 + 255) / 256, 256, 0, stream>>>(Wo, Wo_bf, n4);
  n4 = (HID_ * E_) / 4;
  cast_bf16_kernel<<<(n4 + 255) / 256, 256, 0, stream>>>(W1, W1_bf, n4);
  n4 = (NREG_ * HID_) / 4;
  cast_bf16_kernel<<<(n4 + 255) / 256, 256, 0, stream>>>(W2, W2_bf, n4);

  encode_kernel<<<dim3(R_, 4), 256, 0, stream>>>(x, enc_W, enc_b, starts, redst, yT, pS1b, pS2b);
  bn1_stats_kernel<<<(CONCAT_ + 255) / 256, 256, 0, stream>>>(pS1b, pS2b, mean1, rstd1);
  bn1_transpose_kernel<<<dim3((CONCAT_ + 63) / 64, B_ / 64), 256, 0, stream>>>(yT, mean1, rstd1, bn1_g, bn1_b, Ybf);
  pad_zero_kernel<<<(B_ * 3 + 255) / 256, 256, 0, stream>>>(Ybf);

  // V = Y @ Wv^T + bv  (L=1 softmax == 1 -> attention output == V; q,k never needed)
  gemm_lds_kernel<true><<<dim3(E_ / 128, B_ / 128), 256, 0, stream>>>(
      Ybf, Wv_bf, bqkv + 2 * E_, nullptr, Vbf, B_, E_, E_);
  // O = V @ Wo^T + bo
  gemm_lds_kernel<true><<<dim3(E_ / 128, B_ / 128), 256, 0, stream>>>(
      Vbf, Wo_bf, bo, nullptr, Obf, B_, E_, E_);
  // Z = O @ W1^T + b1
  gemm_lds_kernel<false><<<dim3(HID_ / 128, B_ / 128), 256, 0, stream>>>(
      Obf, W1_bf, b1, Z, nullptr, B_, HID_, E_);

  colstats_partial_kernel<<<dim3(HID_ / 256, 16), 256, 0, stream>>>(Z, partS, partS2, B_, HID_, B_ / 16);
  colstats_final_kernel<<<HID_ / 256, 256, 0, stream>>>(partS, partS2, mean2, rstd2, HID_, 16, B_);
  bn2_apply_kernel<<<(B_ * HID_) / 256, 256, 0, stream>>>(Z, mean2, rstd2, bn2_g, bn2_b, Rbf);

  // reg_out = R @ W2^T + b2
  float* reg_out = (float*)d_out;
  gemm_lds_kernel<false><<<dim3((NREG_ + 127) / 128, B_ / 128), 256, 0, stream>>>(
      Rbf, W2_bf, b2, reg_out, nullptr, B_, NREG_, HID_);

  // y_pred = softmax(reg_out @ Wc^T + bc)
  classifier_kernel<<<B_, 256, 0, stream>>>(reg_out, Wc, bc, reg_out + (size_t)B_ * NREG_);
}

// Round 4
// 531.386 us; speedup vs baseline: 1.6877x; 1.0281x over previous
//
#include <hip/hip_runtime.h>
#include <hip/hip_bf16.h>

#define B_      2048
#define R_      333
#define MAXI_   119
#define MAXO_   12
#define CONCAT_ 3325
#define E_      3328
#define TOTAL_  24696
#define HID_    1024
#define NREG_   300
#define NCLS_   180
#define EPS_    1e-5f
#define NSLOT_  128  // BN1 partial-stat slots (2048 rows / 16 rows-per-block)
#define PSTR_   3328 // partial-stat stride
#define CHN_    25   // 1024-col x chunks
#define XSTR_   1164 // LDS row stride (bf16): <=2-way bank conflicts, 8B-aligned rows

typedef __attribute__((ext_vector_type(8))) short bf16x8;
typedef __attribute__((ext_vector_type(4))) float f32x4;

static __device__ inline unsigned short f2bf_rne(float f) {
  unsigned u;
  __builtin_memcpy(&u, &f, 4);
  u += 0x7fff + ((u >> 16) & 1);     // round-nearest-even; inputs finite
  return (unsigned short)(u >> 16);
}

// ---------------- layout: ROI starts / reduced starts / chunk tables ----------------
__global__ void layout_kernel(int* __restrict__ starts, int* __restrict__ red_starts,
                              int* __restrict__ chunk_first, int* __restrict__ chunk_cnt) {
  if (threadIdx.x == 0 && blockIdx.x == 0) {
    for (int c = 0; c < CHN_; ++c) { chunk_first[c] = 0; chunk_cnt[c] = 0; }
    int s = 0, rs = 0;
    for (int r = 0; r < R_; ++r) {
      starts[r] = s;
      red_starts[r] = rs;
      int c = s >> 10;
      if (chunk_cnt[c] == 0) chunk_first[c] = r;
      chunk_cnt[c]++;
      s += 30 + (7 * r) % 90;
      rs += (r == 332) ? 8 : (8 + r % 5);
    }
  }
}

// ---------------- f32 -> bf16 cast (vectorized) ----------------
__global__ __launch_bounds__(256) void cast_bf16_kernel(const float* __restrict__ src,
                                                        unsigned short* __restrict__ dst, int n4) {
  int i = blockIdx.x * 256 + threadIdx.x;
  if (i >= n4) return;
  float4 v = ((const float4*)src)[i];
  ushort4 o;
  o.x = f2bf_rne(v.x); o.y = f2bf_rne(v.y); o.z = f2bf_rne(v.z); o.w = f2bf_rne(v.w);
  ((ushort4*)dst)[i] = o;
}

// ---------------- pack enc_W into MFMA A-fragment order (bf16, zero beyond size) -------
// Wpk[r][kc][lane][8]: lane holds W[oc=lane&15][k=kc*32+(lane>>4)*8 + e], 0 if k>=size/oc>=12
__global__ __launch_bounds__(256) void pack_w_kernel(const float* __restrict__ enc_W,
                                                     unsigned short* __restrict__ Wpk) {
  int r = blockIdx.x;
  int tid = threadIdx.x;
  int kc = tid >> 6, lane = tid & 63;
  int size = 30 + (7 * r) % 90;
  int oc = lane & 15;
  int k0 = kc * 32 + (lane >> 4) * 8;
  unsigned short o[8];
#pragma unroll
  for (int e = 0; e < 8; ++e) {
    int k = k0 + e;
    float v = 0.f;
    if (oc < MAXO_ && k < size) v = enc_W[((size_t)r * MAXO_ + oc) * MAXI_ + k];
    o[e] = f2bf_rne(v);
  }
  unsigned short* dst = Wpk + ((size_t)r * 4 + kc) * 512 + lane * 8;
  *(ushort4*)dst = *(ushort4*)&o[0];
  *(ushort4*)(dst + 4) = *(ushort4*)&o[4];
}

// ---------------- ragged encoder: LDS-chunked x, MFMA, fused BN1 partials ----------------
// block = (chunk c, batch tile bt of 16 rows). Stage x[bt*16..+16][c*1024 .. +1152) as bf16
// into LDS (coalesced float4 reads), then each wave processes every 4th ROI of the chunk.
__global__ __launch_bounds__(256) void encode_kernel(
    const float* __restrict__ x, const unsigned short* __restrict__ Wpk,
    const float* __restrict__ enc_b, const int* __restrict__ starts,
    const int* __restrict__ red_starts, const int* __restrict__ chunk_first,
    const int* __restrict__ chunk_cnt,
    float* __restrict__ yT, float* __restrict__ pS1, float* __restrict__ pS2) {
  __shared__ unsigned short xt[16][XSTR_];
  int c  = blockIdx.x;
  int bt = blockIdx.y;
  int tid = threadIdx.x;
  int base = c << 10;
  int avail = TOTAL_ - base; if (avail > 1152) avail = 1152;
  int nv4 = (avail + 3) >> 2;

  // --- stage: row = tid>>4 (16 threads/row), 288 float4-slots per row (1152 floats) ---
  {
    int row = tid >> 4, j0 = tid & 15;
    const float* src = x + (size_t)(bt * 16 + row) * TOTAL_ + base;
    for (int j = j0; j < 288; j += 16) {
      float4 v = {0.f, 0.f, 0.f, 0.f};
      if (j < nv4) {
        int gk = base + j * 4;
        if (gk + 4 <= TOTAL_) v = *(const float4*)(src + j * 4);
        else {
          if (gk     < TOTAL_) v.x = src[j * 4];
          if (gk + 1 < TOTAL_) v.y = src[j * 4 + 1];
          if (gk + 2 < TOTAL_) v.z = src[j * 4 + 2];
        }
      }
      ushort4 o;
      o.x = f2bf_rne(v.x); o.y = f2bf_rne(v.y); o.z = f2bf_rne(v.z); o.w = f2bf_rne(v.w);
      *(ushort4*)&xt[row][j * 4] = o;   // 8B store, row stride 2328B (8B-aligned)
    }
  }
  __syncthreads();

  int wid = tid >> 6, lane = tid & 63;
  int lr = lane & 15, kg = lane >> 4;
  int first = chunk_first[c], cnt = chunk_cnt[c];

  for (int ri = wid; ri < cnt; ri += 4) {
    int r = first + ri;
    int size = 30 + (7 * r) % 90;
    int red  = (r == 332) ? 8 : (8 + r % 5);
    int ls   = starts[r] - base;          // 0..1023
    int rs   = red_starts[r];
    int nkc  = (size + 31) >> 5;

    f32x4 acc = {0.f, 0.f, 0.f, 0.f};
    const unsigned short* wp = Wpk + (size_t)r * 2048 + lane * 8;
    for (int kc = 0; kc < nkc; ++kc) {
      bf16x8 wf = *(const bf16x8*)(wp + kc * 512);
      const unsigned short* xp = &xt[lr][ls + kc * 32 + kg * 8];
      bf16x8 xf;
#pragma unroll
      for (int e = 0; e < 8; ++e) xf[e] = (short)xp[e];
      acc = __builtin_amdgcn_mfma_f32_16x16x32_bf16(wf, xf, acc, 0, 0, 0);
    }
    // C layout: col = lane&15 = batch, row = kg*4+reg = oc
#pragma unroll
    for (int reg = 0; reg < 4; ++reg) {
      int oc = kg * 4 + reg;            // uniform across the 16-lane lr group
      if (oc < red) {
        float v = acc[reg] + enc_b[r * MAXO_ + oc];
        yT[(size_t)(rs + oc) * B_ + bt * 16 + lr] = v;
        float a = v, s2 = v * v;
#pragma unroll
        for (int m = 1; m <= 8; m <<= 1) { a += __shfl_xor(a, m); s2 += __shfl_xor(s2, m); }
        if (lr == 0) {
          pS1[bt * PSTR_ + rs + oc] = a;
          pS2[bt * PSTR_ + rs + oc] = s2;
        }
      }
    }
  }
}

// ---------------- BN1 stats finalize (128 slot-partials -> mean/rstd) ----------------
__global__ __launch_bounds__(256) void bn1_stats_kernel(const float* __restrict__ pS1,
                                                        const float* __restrict__ pS2,
                                                        float* __restrict__ mean, float* __restrict__ rstd) {
  int c = blockIdx.x * 256 + threadIdx.x;
  if (c >= CONCAT_) return;
  float s = 0.f, s2 = 0.f;
  for (int i = 0; i < NSLOT_; ++i) { s += pS1[i * PSTR_ + c]; s2 += pS2[i * PSTR_ + c]; }
  float m = s / B_;
  float v = s2 / B_ - m * m;
  mean[c] = m;
  rstd[c] = rsqrtf(v + EPS_);
}

// ---------------- BN1 + LeakyReLU(0.3) + transpose + pad-col write (bf16) ----------------
__global__ __launch_bounds__(256) void bn1_transpose_kernel(
    const float* __restrict__ yT, const float* __restrict__ mean, const float* __restrict__ rstd,
    const float* __restrict__ g, const float* __restrict__ bb, unsigned short* __restrict__ Y) {
  __shared__ float tile[64][65];
  int c0 = blockIdx.x * 64, b0 = blockIdx.y * 64;
  int t = threadIdx.x;
  int bi = t & 63, ci0 = t >> 6;
  for (int ci = ci0; ci < 64; ci += 4) {
    int c = c0 + ci;
    float v = 0.f;
    if (c < CONCAT_) {
      v = (yT[(size_t)c * B_ + b0 + bi] - mean[c]) * rstd[c] * g[c] + bb[c];
      v = v > 0.f ? v : 0.3f * v;
    }
    tile[ci][bi] = v;
  }
  __syncthreads();
  int cj = t & 63, bj0 = t >> 6;
  for (int bj = bj0; bj < 64; bj += 4) {
    int c = c0 + cj;
    if (c < CONCAT_)
      Y[(size_t)(b0 + bj) * E_ + c + 1] = f2bf_rne(tile[cj][bj]);
  }
}

__global__ __launch_bounds__(256) void pad_zero_kernel(unsigned short* __restrict__ Y) {
  int i = blockIdx.x * 256 + threadIdx.x;
  if (i >= B_ * 3) return;
  int b = i / 3, which = i % 3;
  int c = (which == 0) ? 0 : ((which == 1) ? 3326 : 3327);
  Y[(size_t)b * E_ + c] = 0;
}

// ---------------- 2-phase double-buffered bf16 MFMA GEMM: C = A @ W^T + bias ----------------
// 128x128 tile, BK=32. Prefetch next K-tile (global_load_lds x4) BEFORE compute; one
// vmcnt-drain barrier per tile => load latency hides under MFMA (T3-minimum, catalog).
template <bool OUT_BF16>
__global__ __launch_bounds__(256) void gemm_lds_kernel(
    const unsigned short* __restrict__ A, const unsigned short* __restrict__ W,
    const float* __restrict__ bias, float* __restrict__ Cf, unsigned short* __restrict__ Cb,
    int M, int N, int K) {
  __shared__ unsigned short a_lds[2][128 * 32];
  __shared__ unsigned short b_lds[2][128 * 32];
  int tid = threadIdx.x;
  int wid = tid >> 6, lane = tid & 63;
  int wr = wid >> 1, wc = wid & 1;
  int row0 = blockIdx.y * 128, col0 = blockIdx.x * 128;
  int lr = lane & 15, kg = lane >> 4;

  int srow = tid >> 2, sk = (tid & 3) * 8;
  const unsigned short* aptr0 = A + (size_t)(row0 + srow) * K + sk;
  const unsigned short* aptr1 = aptr0 + (size_t)64 * K;
  int bcol0 = col0 + srow;      if (bcol0 > N - 1) bcol0 = N - 1;  // N-tail clamp (discarded)
  int bcol1 = col0 + 64 + srow; if (bcol1 > N - 1) bcol1 = N - 1;
  const unsigned short* bptr0 = W + (size_t)bcol0 * K + sk;
  const unsigned short* bptr1 = W + (size_t)bcol1 * K + sk;

  f32x4 acc[4][4] = {};
  int nk = K >> 5;

#define STAGE_(buf, kc)                                                                         \
  do {                                                                                          \
    __builtin_amdgcn_global_load_lds((const __attribute__((address_space(1))) void*)(aptr0 + (kc)), \
        (__attribute__((address_space(3))) void*)(&a_lds[buf][wid * 512]), 16, 0, 0);           \
    __builtin_amdgcn_global_load_lds((const __attribute__((address_space(1))) void*)(aptr1 + (kc)), \
        (__attribute__((address_space(3))) void*)(&a_lds[buf][2048 + wid * 512]), 16, 0, 0);    \
    __builtin_amdgcn_global_load_lds((const __attribute__((address_space(1))) void*)(bptr0 + (kc)), \
        (__attribute__((address_space(3))) void*)(&b_lds[buf][wid * 512]), 16, 0, 0);          \
    __builtin_amdgcn_global_load_lds((const __attribute__((address_space(1))) void*)(bptr1 + (kc)), \
        (__attribute__((address_space(3))) void*)(&b_lds[buf][2048 + wid * 512]), 16, 0, 0);   \
  } while (0)

  STAGE_(0, 0);
  __syncthreads();                       // drain: buf0 resident
  int cur = 0;
  for (int t = 0; t < nk; ++t) {
    if (t + 1 < nk) STAGE_(cur ^ 1, (t + 1) * 32);   // prefetch rides under MFMA
    bf16x8 a[4], b[4];
#pragma unroll
    for (int f = 0; f < 4; ++f) {
      a[f] = *(const bf16x8*)&a_lds[cur][(wr * 64 + f * 16 + lr) * 32 + kg * 8];
      b[f] = *(const bf16x8*)&b_lds[cur][(wc * 64 + f * 16 + lr) * 32 + kg * 8];
    }
#pragma unroll
    for (int i = 0; i < 4; ++i)
#pragma unroll
      for (int j = 0; j < 4; ++j)
        acc[i][j] = __builtin_amdgcn_mfma_f32_16x16x32_bf16(a[i], b[j], acc[i][j], 0, 0, 0);
    __syncthreads();                     // drain prefetch + protect buf reuse
    cur ^= 1;
  }
#undef STAGE_

  // C/D: col = lane&15, row = (lane>>4)*4 + reg
#pragma unroll
  for (int j = 0; j < 4; ++j) {
    int ccol = col0 + wc * 64 + j * 16 + lr;
    if (ccol >= N) continue;
    float bv = bias[ccol];
#pragma unroll
    for (int i = 0; i < 4; ++i) {
#pragma unroll
      for (int reg = 0; reg < 4; ++reg) {
        int crow = row0 + wr * 64 + i * 16 + kg * 4 + reg;
        float v = acc[i][j][reg] + bv;
        if (OUT_BF16) Cb[(size_t)crow * N + ccol] = f2bf_rne(v);
        else          Cf[(size_t)crow * N + ccol] = v;
      }
    }
  }
}

// ---------------- BN2 stats over row-major Z (two-stage, deterministic) ----------------
__global__ __launch_bounds__(256) void colstats_partial_kernel(
    const float* __restrict__ Z, float* __restrict__ pS, float* __restrict__ pS2,
    int M, int C, int rowsPerBlock) {
  int c = blockIdx.x * 256 + threadIdx.x;
  if (c >= C) return;
  int r0 = blockIdx.y * rowsPerBlock;
  float s = 0.f, s2 = 0.f;
  for (int r = r0; r < r0 + rowsPerBlock; ++r) {
    float v = Z[(size_t)r * C + c];
    s += v; s2 = fmaf(v, v, s2);
  }
  pS[blockIdx.y * C + c] = s;
  pS2[blockIdx.y * C + c] = s2;
}

__global__ __launch_bounds__(256) void colstats_final_kernel(
    const float* __restrict__ pS, const float* __restrict__ pS2,
    float* __restrict__ mean, float* __restrict__ rstd, int C, int nrb, int M) {
  int c = blockIdx.x * 256 + threadIdx.x;
  if (c >= C) return;
  float s = 0.f, s2 = 0.f;
  for (int i = 0; i < nrb; ++i) { s += pS[i * C + c]; s2 += pS2[i * C + c]; }
  float m = s / M;
  float v = s2 / M - m * m;
  mean[c] = m;
  rstd[c] = rsqrtf(v + EPS_);
}

// ---------------- BN2 apply + LeakyReLU(0.1) -> bf16 ----------------
__global__ __launch_bounds__(256) void bn2_apply_kernel(
    const float* __restrict__ Z, const float* __restrict__ mean, const float* __restrict__ rstd,
    const float* __restrict__ g, const float* __restrict__ bb, unsigned short* __restrict__ R) {
  int i = blockIdx.x * 256 + threadIdx.x;
  int c = i & (HID_ - 1);
  float v = (Z[i] - mean[c]) * rstd[c] * g[c] + bb[c];
  v = v > 0.f ? v : 0.1f * v;
  R[i] = f2bf_rne(v);
}

// ---------------- classifier: y_pred = softmax(reg @ Wc^T + bc) ----------------
__global__ __launch_bounds__(256) void classifier_kernel(
    const float* __restrict__ reg, const float* __restrict__ Wc, const float* __restrict__ bc,
    float* __restrict__ ypred) {
  int b = blockIdx.x;
  __shared__ __align__(16) float rrow[NREG_];
  __shared__ float sl[256];
  int tid = threadIdx.x;
  for (int i = tid; i < NREG_; i += 256) rrow[i] = reg[(size_t)b * NREG_ + i];
  __syncthreads();
  float s = -1e30f;
  if (tid < NCLS_) {
    const float* w = Wc + (size_t)tid * NREG_;
    float acc = 0.f;
    for (int k = 0; k < NREG_; k += 4) {
      float4 wv = *(const float4*)(w + k);
      float4 rv = *(const float4*)(&rrow[k]);
      acc = fmaf(wv.x, rv.x, acc); acc = fmaf(wv.y, rv.y, acc);
      acc = fmaf(wv.z, rv.z, acc); acc = fmaf(wv.w, rv.w, acc);
    }
    s = acc + bc[tid];
  }
  sl[tid] = s;
  __syncthreads();
  for (int o = 128; o > 0; o >>= 1) {
    if (tid < o) sl[tid] = fmaxf(sl[tid], sl[tid + o]);
    __syncthreads();
  }
  float mx = sl[0];
  __syncthreads();
  float e = (tid < NCLS_) ? __expf(s - mx) : 0.f;
  sl[tid] = e;
  __syncthreads();
  for (int o = 128; o > 0; o >>= 1) {
    if (tid < o) sl[tid] += sl[tid + o];
    __syncthreads();
  }
  if (tid < NCLS_) ypred[(size_t)b * NCLS_ + tid] = e / sl[0];
}

// ---------------- host orchestration ----------------
extern "C" void kernel_launch(void* const* d_in, const int* in_sizes, int n_in,
                              void* d_out, int out_size, void* d_ws, size_t ws_size,
                              hipStream_t stream) {
  const float* x     = (const float*)d_in[0];
  const float* enc_W = (const float*)d_in[1];
  const float* enc_b = (const float*)d_in[2];
  const float* bn1_g = (const float*)d_in[3];
  const float* bn1_b = (const float*)d_in[4];
  const float* Wqkv  = (const float*)d_in[5];
  const float* bqkv  = (const float*)d_in[6];
  const float* Wo    = (const float*)d_in[7];
  const float* bo    = (const float*)d_in[8];
  const float* W1    = (const float*)d_in[9];
  const float* b1    = (const float*)d_in[10];
  const float* bn2_g = (const float*)d_in[11];
  const float* bn2_b = (const float*)d_in[12];
  const float* W2    = (const float*)d_in[13];
  const float* b2    = (const float*)d_in[14];
  const float* Wc    = (const float*)d_in[15];
  const float* bc    = (const float*)d_in[16];

  char* ws = (char*)d_ws;
  size_t off = 0;
  auto alloc = [&](size_t bytes) -> void* {
    void* p = ws + off;
    off += (bytes + 255) & ~(size_t)255;
    return p;
  };

  float*          yT     = (float*)alloc((size_t)CONCAT_ * B_ * 4);       // reused for Z
  float*          pS1b   = (float*)alloc((size_t)NSLOT_ * PSTR_ * 4);
  float*          pS2b   = (float*)alloc((size_t)NSLOT_ * PSTR_ * 4);
  float*          mean1  = (float*)alloc(CONCAT_ * 4);
  float*          rstd1  = (float*)alloc(CONCAT_ * 4);
  unsigned short* Ybf    = (unsigned short*)alloc((size_t)B_ * E_ * 2);   // reused for O
  unsigned short* Vbf    = (unsigned short*)alloc((size_t)B_ * E_ * 2);   // reused for R
  unsigned short* Wv_bf  = (unsigned short*)alloc((size_t)E_ * E_ * 2);
  unsigned short* Wo_bf  = (unsigned short*)alloc((size_t)E_ * E_ * 2);
  unsigned short* W1_bf  = (unsigned short*)alloc((size_t)HID_ * E_ * 2);
  unsigned short* W2_bf  = (unsigned short*)alloc((size_t)NREG_ * HID_ * 2);
  unsigned short* Wpk    = (unsigned short*)alloc((size_t)R_ * 2048 * 2); // packed enc_W frags
  float*          partS  = (float*)alloc(16 * HID_ * 4);
  float*          partS2 = (float*)alloc(16 * HID_ * 4);
  float*          mean2  = (float*)alloc(HID_ * 4);
  float*          rstd2  = (float*)alloc(HID_ * 4);
  int*            starts = (int*)alloc(R_ * 4);
  int*            redst  = (int*)alloc(R_ * 4);
  int*            chF    = (int*)alloc(CHN_ * 4);
  int*            chC    = (int*)alloc(CHN_ * 4);

  unsigned short* Obf = Ybf;
  float*          Z   = yT;
  unsigned short* Rbf = Vbf;

  layout_kernel<<<1, 1, 0, stream>>>(starts, redst, chF, chC);
  pack_w_kernel<<<R_, 256, 0, stream>>>(enc_W, Wpk);

  int n4 = (E_ * E_) / 4;
  cast_bf16_kernel<<<(n4 + 255) / 256, 256, 0, stream>>>(Wqkv + (size_t)2 * E_ * E_, Wv_bf, n4);
  cast_bf16_kernel<<<(n4 + 255) / 256, 256, 0, stream>>>(Wo, Wo_bf, n4);
  n4 = (HID_ * E_) / 4;
  cast_bf16_kernel<<<(n4 + 255) / 256, 256, 0, stream>>>(W1, W1_bf, n4);
  n4 = (NREG_ * HID_) / 4;
  cast_bf16_kernel<<<(n4 + 255) / 256, 256, 0, stream>>>(W2, W2_bf, n4);

  encode_kernel<<<dim3(CHN_, B_ / 16), 256, 0, stream>>>(
      x, Wpk, enc_b, starts, redst, chF, chC, yT, pS1b, pS2b);
  bn1_stats_kernel<<<(CONCAT_ + 255) / 256, 256, 0, stream>>>(pS1b, pS2b, mean1, rstd1);
  bn1_transpose_kernel<<<dim3((CONCAT_ + 63) / 64, B_ / 64), 256, 0, stream>>>(
      yT, mean1, rstd1, bn1_g, bn1_b, Ybf);
  pad_zero_kernel<<<(B_ * 3 + 255) / 256, 256, 0, stream>>>(Ybf);

  // V = Y @ Wv^T + bv  (L=1 softmax == 1 -> attention output == V; q,k never needed)
  gemm_lds_kernel<true><<<dim3(E_ / 128, B_ / 128), 256, 0, stream>>>(
      Ybf, Wv_bf, bqkv + 2 * E_, nullptr, Vbf, B_, E_, E_);
  // O = V @ Wo^T + bo
  gemm_lds_kernel<true><<<dim3(E_ / 128, B_ / 128), 256, 0, stream>>>(
      Vbf, Wo_bf, bo, nullptr, Obf, B_, E_, E_);
  // Z = O @ W1^T + b1
  gemm_lds_kernel<false><<<dim3(HID_ / 128, B_ / 128), 256, 0, stream>>>(
      Obf, W1_bf, b1, Z, nullptr, B_, HID_, E_);

  colstats_partial_kernel<<<dim3(HID_ / 256, 16), 256, 0, stream>>>(Z, partS, partS2, B_, HID_, B_ / 16);
  colstats_final_kernel<<<HID_ / 256, 256, 0, stream>>>(partS, partS2, mean2, rstd2, HID_, 16, B_);
  bn2_apply_kernel<<<(B_ * HID_) / 256, 256, 0, stream>>>(Z, mean2, rstd2, bn2_g, bn2_b, Rbf);

  // reg_out = R @ W2^T + b2
  float* reg_out = (float*)d_out;
  gemm_lds_kernel<false><<<dim3((NREG_ + 127) / 128, B_ / 128), 256, 0, stream>>>(
      Rbf, W2_bf, b2, reg_out, nullptr, B_, NREG_, HID_);

  // y_pred = softmax(reg_out @ Wc^T + bc)
  classifier_kernel<<<B_, 256, 0, stream>>>(reg_out, Wc, bc, reg_out + (size_t)B_ * NREG_);
}